// Round 1
// baseline (424.731 us; speedup 1.0000x reference)
//
#include <hip/hip_runtime.h>

#define N_NODES 100000
#define N_EDGES 1600000
#define LAT 128
#define MAT 8
#define OUTC 3

// ---------------- CSR build ----------------

__global__ void k_count(const int* __restrict__ dst, int* __restrict__ cnt) {
    int e = blockIdx.x * blockDim.x + threadIdx.x;
    if (e < N_EDGES) atomicAdd(&cnt[dst[e]], 1);
}

__global__ void k_dinv(const int* __restrict__ cnt, float* __restrict__ dinv) {
    int i = blockIdx.x * blockDim.x + threadIdx.x;
    if (i < N_NODES) dinv[i] = rsqrtf((float)cnt[i] + 1.0f);  // +1 self-loop
}

// exclusive scan, 1024 elements per block (256 threads x 4)
__global__ __launch_bounds__(256) void k_scan1(const int* __restrict__ cnt,
                                               int* __restrict__ rowptr,
                                               int* __restrict__ blockSums) {
    __shared__ int wsum[4];
    int t = threadIdx.x;
    int lane = t & 63, w = t >> 6;
    int idx = blockIdx.x * 1024 + t * 4;
    int v0 = (idx + 0 < N_NODES) ? cnt[idx + 0] : 0;
    int v1 = (idx + 1 < N_NODES) ? cnt[idx + 1] : 0;
    int v2 = (idx + 2 < N_NODES) ? cnt[idx + 2] : 0;
    int v3 = (idx + 3 < N_NODES) ? cnt[idx + 3] : 0;
    int ts = v0 + v1 + v2 + v3;
    int x = ts;
#pragma unroll
    for (int off = 1; off < 64; off <<= 1) {
        int y = __shfl_up(x, off, 64);
        if (lane >= off) x += y;
    }
    if (lane == 63) wsum[w] = x;
    __syncthreads();
    int wo = 0;
#pragma unroll
    for (int i = 0; i < 4; ++i)
        if (i < w) wo += wsum[i];
    int base = wo + x - ts;  // exclusive prefix for this thread's first element
    if (idx + 0 < N_NODES) rowptr[idx + 0] = base;
    if (idx + 1 < N_NODES) rowptr[idx + 1] = base + v0;
    if (idx + 2 < N_NODES) rowptr[idx + 2] = base + v0 + v1;
    if (idx + 3 < N_NODES) rowptr[idx + 3] = base + v0 + v1 + v2;
    if (t == 255) blockSums[blockIdx.x] = wo + x;  // block total
}

__global__ void k_scan2(int* __restrict__ blockSums, int nb) {
    if (threadIdx.x == 0 && blockIdx.x == 0) {
        int run = 0;
        for (int i = 0; i < nb; ++i) { int v = blockSums[i]; blockSums[i] = run; run += v; }
    }
}

__global__ void k_scan3(int* __restrict__ rowptr, const int* __restrict__ blockSums,
                        int* __restrict__ cursor) {
    int i = blockIdx.x * blockDim.x + threadIdx.x;
    if (i < N_NODES) {
        int r = rowptr[i] + blockSums[i >> 10];
        rowptr[i] = r;
        cursor[i] = r;
    }
    if (i == 0) rowptr[N_NODES] = N_EDGES;
}

__global__ void k_scatter(const int* __restrict__ src, const int* __restrict__ dst,
                          int* __restrict__ cursor, int* __restrict__ colsrc) {
    int e = blockIdx.x * blockDim.x + threadIdx.x;
    if (e < N_EDGES) {
        int d = dst[e];
        int pos = atomicAdd(&cursor[d], 1);
        colsrc[pos] = src[e];
    }
}

// ---------------- GEMM1: g1 = (concat(z, mat) @ W1) * dinv[n] ----------------
// block = 256 threads, 32 nodes/block. thread -> group g = tid>>5 (4 nodes),
// output quad jq = (tid&31)*4. W1 (136x128 = 69.6KB) staged in LDS.
__global__ __launch_bounds__(256) void k_gemm1(const float* __restrict__ z,
                                               const float* __restrict__ mat,
                                               const float* __restrict__ W1,
                                               const float* __restrict__ dinv,
                                               float* __restrict__ g1) {
    __shared__ float w1s[(LAT + MAT) * LAT];
    for (int i = threadIdx.x; i < (LAT + MAT) * LAT; i += 256) w1s[i] = W1[i];
    __syncthreads();
    int g = threadIdx.x >> 5;
    int jq = (threadIdx.x & 31) * 4;
    int n0 = blockIdx.x * 32 + g * 4;
    float acc[4][4] = {{0.f}};
    // z part: k = 0..127
    for (int k4 = 0; k4 < 32; ++k4) {
        float w[4][4];
#pragma unroll
        for (int t = 0; t < 4; ++t)
            *(float4*)&w[t][0] = *(const float4*)&w1s[(k4 * 4 + t) * LAT + jq];
#pragma unroll
        for (int i = 0; i < 4; ++i) {
            float4 xv = *(const float4*)&z[(size_t)(n0 + i) * LAT + k4 * 4];
#pragma unroll
            for (int c = 0; c < 4; ++c)
                acc[i][c] += xv.x * w[0][c] + xv.y * w[1][c] + xv.z * w[2][c] + xv.w * w[3][c];
        }
    }
    // mat part: k = 128..135
#pragma unroll
    for (int h = 0; h < 2; ++h) {
        float w[4][4];
#pragma unroll
        for (int t = 0; t < 4; ++t)
            *(float4*)&w[t][0] = *(const float4*)&w1s[(LAT + h * 4 + t) * LAT + jq];
#pragma unroll
        for (int i = 0; i < 4; ++i) {
            float4 xv = *(const float4*)&mat[(size_t)(n0 + i) * MAT + h * 4];
#pragma unroll
            for (int c = 0; c < 4; ++c)
                acc[i][c] += xv.x * w[0][c] + xv.y * w[1][c] + xv.z * w[2][c] + xv.w * w[3][c];
        }
    }
#pragma unroll
    for (int i = 0; i < 4; ++i) {
        float d = dinv[n0 + i];
        float4 o = make_float4(acc[i][0] * d, acc[i][1] * d, acc[i][2] * d, acc[i][3] * d);
        *(float4*)&g1[(size_t)(n0 + i) * LAT + jq] = o;
    }
}

// ---------------- gather layer1 + fused 128x3 GEMM2 ----------------
// one wave per node; lane holds float2 of the 128-wide row.
// x1 = relu(dinv[n]*(g1[n] + sum g1[src]) + b1); g2[n] = (x1 @ W2) * dinv[n]
__global__ __launch_bounds__(256) void k_gather1(const float* __restrict__ g1,
                                                 const int* __restrict__ colsrc,
                                                 const int* __restrict__ rowptr,
                                                 const float* __restrict__ dinv,
                                                 const float* __restrict__ b1,
                                                 const float* __restrict__ W2,
                                                 float* __restrict__ g2) {
    int n = blockIdx.x * 4 + (threadIdx.x >> 6);
    int lane = threadIdx.x & 63;
    const float2* g1v = (const float2*)g1;
    float2 a = g1v[(size_t)n * 64 + lane];
    float ax = a.x, ay = a.y;
    int e = rowptr[n], eEnd = rowptr[n + 1];
    for (; e + 4 <= eEnd; e += 4) {
        int s0 = colsrc[e], s1 = colsrc[e + 1], s2 = colsrc[e + 2], s3 = colsrc[e + 3];
        float2 v0 = g1v[(size_t)s0 * 64 + lane];
        float2 v1 = g1v[(size_t)s1 * 64 + lane];
        float2 v2 = g1v[(size_t)s2 * 64 + lane];
        float2 v3 = g1v[(size_t)s3 * 64 + lane];
        ax += v0.x + v1.x + v2.x + v3.x;
        ay += v0.y + v1.y + v2.y + v3.y;
    }
    for (; e < eEnd; ++e) {
        int s = colsrc[e];
        float2 v = g1v[(size_t)s * 64 + lane];
        ax += v.x; ay += v.y;
    }
    float d = dinv[n];
    float2 bb = ((const float2*)b1)[lane];
    float x0 = fmaxf(ax * d + bb.x, 0.f);
    float x1 = fmaxf(ay * d + bb.y, 0.f);
    float p0 = x0 * W2[(2 * lane) * OUTC + 0] + x1 * W2[(2 * lane + 1) * OUTC + 0];
    float p1 = x0 * W2[(2 * lane) * OUTC + 1] + x1 * W2[(2 * lane + 1) * OUTC + 1];
    float p2 = x0 * W2[(2 * lane) * OUTC + 2] + x1 * W2[(2 * lane + 1) * OUTC + 2];
#pragma unroll
    for (int off = 32; off > 0; off >>= 1) {
        p0 += __shfl_down(p0, off, 64);
        p1 += __shfl_down(p1, off, 64);
        p2 += __shfl_down(p2, off, 64);
    }
    if (lane == 0) ((float4*)g2)[n] = make_float4(p0 * d, p1 * d, p2 * d, 0.f);
}

// ---------------- gather layer2: out = dinv[n]*(g2[n] + sum g2[src]) + b2 ----------------
__global__ void k_gather2(const float* __restrict__ g2, const int* __restrict__ colsrc,
                          const int* __restrict__ rowptr, const float* __restrict__ dinv,
                          const float* __restrict__ b2, float* __restrict__ out) {
    int n = blockIdx.x * blockDim.x + threadIdx.x;
    if (n >= N_NODES) return;
    const float4* gv = (const float4*)g2;
    float4 a = gv[n];
    float s0 = a.x, s1 = a.y, s2 = a.z;
    int eEnd = rowptr[n + 1];
    for (int e = rowptr[n]; e < eEnd; ++e) {
        float4 v = gv[colsrc[e]];
        s0 += v.x; s1 += v.y; s2 += v.z;
    }
    float d = dinv[n];
    out[(size_t)n * 3 + 0] = s0 * d + b2[0];
    out[(size_t)n * 3 + 1] = s1 * d + b2[1];
    out[(size_t)n * 3 + 2] = s2 * d + b2[2];
}

// ---------------- launch ----------------

extern "C" void kernel_launch(void* const* d_in, const int* in_sizes, int n_in,
                              void* d_out, int out_size, void* d_ws, size_t ws_size,
                              hipStream_t stream) {
    const float* z   = (const float*)d_in[0];
    const int*   ei  = (const int*)d_in[1];   // [2, E] int32
    const float* mat = (const float*)d_in[2];
    const float* W1  = (const float*)d_in[3];
    const float* b1  = (const float*)d_in[4];
    const float* W2  = (const float*)d_in[5];
    const float* b2  = (const float*)d_in[6];
    float* out = (float*)d_out;

    const int* srcA = ei;             // row 0 = message source
    const int* dstA = ei + N_EDGES;   // row 1 = message target

    char* ws = (char*)d_ws;
    auto alloc = [&](size_t bytes) {
        char* p = ws;
        ws += (bytes + 255) & ~(size_t)255;
        return p;
    };
    int*   cnt       = (int*)alloc((size_t)N_NODES * 4);
    int*   rowptr    = (int*)alloc((size_t)(N_NODES + 1) * 4);
    int*   cursor    = (int*)alloc((size_t)N_NODES * 4);
    float* dinv      = (float*)alloc((size_t)N_NODES * 4);
    int*   blockSums = (int*)alloc(512);
    int*   colsrc    = (int*)alloc((size_t)N_EDGES * 4);
    float* g1        = (float*)alloc((size_t)N_NODES * LAT * 4);
    float* g2        = (float*)alloc((size_t)N_NODES * 4 * 4);

    int nScanBlocks = (N_NODES + 1023) / 1024;

    hipMemsetAsync(cnt, 0, (size_t)N_NODES * 4, stream);
    k_count<<<(N_EDGES + 255) / 256, 256, 0, stream>>>(dstA, cnt);
    k_dinv<<<(N_NODES + 255) / 256, 256, 0, stream>>>(cnt, dinv);
    k_scan1<<<nScanBlocks, 256, 0, stream>>>(cnt, rowptr, blockSums);
    k_scan2<<<1, 64, 0, stream>>>(blockSums, nScanBlocks);
    k_scan3<<<(N_NODES + 255) / 256, 256, 0, stream>>>(rowptr, blockSums, cursor);
    k_scatter<<<(N_EDGES + 255) / 256, 256, 0, stream>>>(srcA, dstA, cursor, colsrc);
    k_gemm1<<<N_NODES / 32, 256, 0, stream>>>(z, mat, W1, dinv, g1);
    k_gather1<<<N_NODES / 4, 256, 0, stream>>>(g1, colsrc, rowptr, dinv, b1, W2, g2);
    k_gather2<<<(N_NODES + 255) / 256, 256, 0, stream>>>(g2, colsrc, rowptr, dinv, b2, out);
}